// Round 13
// baseline (218.995 us; speedup 1.0000x reference)
//
#include <hip/hip_runtime.h>
#include <stdint.h>

// Binarized 3-layer CNN — bit-exact vs float32 reference (verified r3-r12).
// L1: f32 conv, strict sequential (kh,kw,c) per-pixel order, 8 px/thread,
//     weights via wave-uniform s_load at use (r8 best-measured form),
//     asm alignbit funnel epilogue.
// L2: XOR+popcount vs NEGATIVE masks, 1 px/thread, weights via uniform
//     s_load; bcnt chain seeded from SGPR(-72). Exact ternary fallback.
// L3: masked-popcount ternary conv, 4 px/thread (r8-verified).

#define H1 510
#define H2 508
#define H3 506
#define STRIDE 512

#define BCNT_ACC(acc, x) \
    asm("v_bcnt_u32_b32 %0, %1, %0" : "+v"(acc) : "v"(x))
#define BCNT_SEED(dst, x, seed) \
    asm("v_bcnt_u32_b32 %0, %1, %2" : "=v"(dst) : "v"(x), "s"(seed))
#define FUNNEL31(word, val) \
    asm("v_alignbit_b32 %0, %0, %1, 31" : "+v"(word) : "v"(val))

__global__ __launch_bounds__(256) void k_prep(const float* __restrict__ w1,
                                              const float* __restrict__ w2,
                                              const float* __restrict__ w3,
                                              float* __restrict__ lw,
                                              uint32_t* __restrict__ pw2c,
                                              uint32_t* __restrict__ pw3) {
    int t = threadIdx.x;
    // sign(w1), order t=(r*3+j)*3+c (c fastest), padded to 28/o
    for (int i = t; i < 448; i += 256) {
        int o = i / 28, k = i % 28;
        float v = 0.f;
        if (k < 27) {
            int c = k % 3, j = (k / 3) % 3, r = k / 9;
            float wv = w1[o * 27 + c * 9 + r * 3 + j];
            v = (wv > 0.f) ? 1.f : ((wv < 0.f) ? -1.f : 0.f);
        }
        lw[i] = v;
    }
    // w2 [23][16][3][3] -> pw2c[o*5+g]: NEGATIVE-mask 16-bit channel words,
    // 2 taps/word (k0 lo16, k1 hi16); g==4 hi16 = 0. Compact stride 5.
    for (int i = t; i < 115; i += 256) {
        int o = i / 5, g = i % 5;
        int k0 = 2 * g, k1 = 2 * g + 1;
        uint32_t word = 0;
        for (int c = 0; c < 16; ++c) {
            if (!(w2[o * 144 + c * 9 + k0] > 0.f)) word |= 1u << c;
            if (k1 < 9 && !(w2[o * 144 + c * 9 + k1] > 0.f)) word |= 1u << (16 + c);
        }
        pw2c[i] = word;
    }
    // w3 [2][23][3][3] -> per (o, tap k): POSITIVE 23-bit channel mask
    for (int i = t; i < 18; i += 256) {
        int o = i / 9, k = i % 9;
        uint32_t m = 0;
        for (int c = 0; c < 23; ++c)
            if (w3[o * 207 + c * 9 + k] > 0.f) m |= 1u << c;
        pw3[i] = m;
    }
}

// 8 px/thread (4 wide x 2 tall); strict per-pixel (kh,kw,c) f32 order.
// Weights via wave-uniform global reads -> scalar loads on the SMEM pipe.
__global__ __launch_bounds__(256) void k_conv1(const float* __restrict__ in,
                                               const float* __restrict__ lw_g,
                                               uint32_t* __restrict__ t1) {
    int gx = blockIdx.x * 64 + threadIdx.x;   // 0..127
    int hy = blockIdx.y * 4 + threadIdx.y;    // 0..255
    int b = blockIdx.z;
    int w0 = gx * 4;                          // 0..508
    int h0 = hy * 2;                          // 0..510
    if (h0 >= H1) return;
    const float* base = in + (size_t)b * 3 * 512 * 512;
    float x[3][4][6];
    bool tail = (w0 + 4 >= 512);
#pragma unroll
    for (int c = 0; c < 3; ++c)
#pragma unroll
        for (int r = 0; r < 4; ++r) {
            const float* rp = base + c * 262144 + (size_t)(h0 + r) * 512 + w0;
            float4 v4 = *(const float4*)rp;
            x[c][r][0] = v4.x; x[c][r][1] = v4.y; x[c][r][2] = v4.z; x[c][r][3] = v4.w;
            if (!tail) {
                float2 v2 = *(const float2*)(rp + 4);
                x[c][r][4] = v2.x; x[c][r][5] = v2.y;
            } else {
                x[c][r][4] = 0.f; x[c][r][5] = 0.f;   // feeds only px >= H1 (unread)
            }
        }
    uint32_t rn[8] = {0, 0, 0, 0, 0, 0, 0, 0};   // sign-bit planes
    uint32_t rz[8] = {0, 0, 0, 0, 0, 0, 0, 0};   // NONZERO-bit planes
#pragma unroll 1
    for (int o = 15; o >= 0; --o) {              // o order irrelevant to rounding
        const float* wo = lw_g + o * 28;         // uniform address -> s_load
        float s[8];
#pragma unroll
        for (int p = 0; p < 8; ++p) s[p] = 0.f;
#pragma unroll
        for (int t = 0; t < 27; ++t) {           // ascending t = (r*3+j)*3+c
            float wv = wo[t];
            int c = t % 3, j = (t / 3) % 3, r = t / 9;
#pragma unroll
            for (int pr = 0; pr < 2; ++pr)
#pragma unroll
                for (int pc = 0; pc < 4; ++pc)
                    s[pr * 4 + pc] = fmaf(x[c][pr + r][pc + j], wv, s[pr * 4 + pc]);
        }
#pragma unroll
        for (int p = 0; p < 8; ++p) {
            uint32_t u = __float_as_uint(s[p]);
            FUNNEL31(rn[p], u);                  // rn = (rn<<1) | (u>>31)
            uint32_t nz = u | (0u - u);          // sign set iff u != 0
            FUNNEL31(rz[p], nz);                 // rz = (rz<<1) | (nz>>31)
        }
    }
    uint32_t* dst = t1 + (size_t)b * H1 * STRIDE;
#pragma unroll
    for (int pr = 0; pr < 2; ++pr) {
        uint32_t w4[4];
#pragma unroll
        for (int pc = 0; pc < 4; ++pc)
            w4[pc] = rn[pr * 4 + pc] | (~rz[pr * 4 + pc] << 16);  // n lo16 | z hi16
        *(uint4*)(dst + (size_t)(h0 + pr) * STRIDE + w0) =
            make_uint4(w4[0], w4[1], w4[2], w4[3]);
    }
}

// 1 px/thread; weights via uniform s_load (SGPRs), chunked to bound pressure.
__global__ __launch_bounds__(256) void k_conv2(const uint32_t* __restrict__ t1,
                                               const uint32_t* __restrict__ wc5,
                                               uint32_t* __restrict__ p2,
                                               uint32_t* __restrict__ m2) {
    int w = blockIdx.x * 64 + threadIdx.x;
    int h = blockIdx.y * 4 + threadIdx.y;
    int b = blockIdx.z;
    if (w >= H2 || h >= H2) return;
    const uint32_t* base = t1 + (size_t)b * H1 * STRIDE;
    uint32_t A[9];
#pragma unroll
    for (int r = 0; r < 3; ++r)
#pragma unroll
        for (int j = 0; j < 3; ++j)
            A[r * 3 + j] = base[(size_t)(h + r) * STRIDE + (w + j)];
    uint32_t orall = A[0] | A[1] | A[2] | A[3] | A[4] | A[5] | A[6] | A[7] | A[8];
    // n-plane packed 2 taps/word via byte-perm
    uint32_t N0 = __builtin_amdgcn_perm(A[1], A[0], 0x05040100u);
    uint32_t N1 = __builtin_amdgcn_perm(A[3], A[2], 0x05040100u);
    uint32_t N2 = __builtin_amdgcn_perm(A[5], A[4], 0x05040100u);
    uint32_t N3 = __builtin_amdgcn_perm(A[7], A[6], 0x05040100u);
    uint32_t N4 = A[8] & 0xFFFFu;
    uint32_t plus = 0, minus = 0;
    if ((orall >> 16) == 0) {
        // FAST: all 144 activations +-1. d = popc_mismatch - 72; o descending.
        int seed = -72;                      // wave-uniform -> SGPR
#define C2O(o) do { \
        uint32_t q0 = wc5[(o) * 5 + 0], q1 = wc5[(o) * 5 + 1], \
                 q2 = wc5[(o) * 5 + 2], q3 = wc5[(o) * 5 + 3], \
                 q4 = wc5[(o) * 5 + 4]; \
        uint32_t t0 = N0 ^ q0, t1v = N1 ^ q1, t2v = N2 ^ q2, \
                 t3v = N3 ^ q3, t4v = N4 ^ q4; \
        int cnt; \
        BCNT_SEED(cnt, t0, seed); \
        BCNT_ACC(cnt, t1v); BCNT_ACC(cnt, t2v); \
        BCNT_ACC(cnt, t3v); BCNT_ACC(cnt, t4v); \
        int nd = -cnt; \
        FUNNEL31(plus, cnt); \
        FUNNEL31(minus, nd); \
    } while (0)
        C2O(22); C2O(21); C2O(20); C2O(19); C2O(18); C2O(17); C2O(16); C2O(15);
        __builtin_amdgcn_sched_barrier(0);
        C2O(14); C2O(13); C2O(12); C2O(11); C2O(10); C2O(9); C2O(8); C2O(7);
        __builtin_amdgcn_sched_barrier(0);
        C2O(6); C2O(5); C2O(4); C2O(3); C2O(2); C2O(1); C2O(0);
#undef C2O
    } else {
        // RARE: window contains an exact-zero L1 activation -> exact ternary.
        uint32_t P[5], M[5];
        {
            uint32_t p16[9], m16[9];
#pragma unroll
            for (int k = 0; k < 9; ++k) {
                uint32_t z = A[k] >> 16;
                p16[k] = (~(A[k] | z)) & 0xFFFFu;
                m16[k] = (A[k] & ~z) & 0xFFFFu;
            }
            P[0] = p16[0] | (p16[1] << 16); M[0] = m16[0] | (m16[1] << 16);
            P[1] = p16[2] | (p16[3] << 16); M[1] = m16[2] | (m16[3] << 16);
            P[2] = p16[4] | (p16[5] << 16); M[2] = m16[4] | (m16[5] << 16);
            P[3] = p16[6] | (p16[7] << 16); M[3] = m16[6] | (m16[7] << 16);
            P[4] = p16[8];                  M[4] = m16[8];
        }
        int sp = 0, sm = 0;
#pragma unroll
        for (int g = 0; g < 5; ++g) {
            sp += __builtin_popcount(P[g]);
            sm += __builtin_popcount(M[g]);
        }
#pragma unroll
        for (int o = 0; o < 23; ++o) {
            int ap = 0, am = 0;
#pragma unroll
            for (int g = 0; g < 5; ++g) {
                uint32_t Wn = wc5[o * 5 + g];   // uniform s_load
                ap += __builtin_popcount(P[g] & Wn);
                am += __builtin_popcount(M[g] & Wn);
            }
            int s = sp - sm + 2 * (am - ap);
            plus  |= (uint32_t)(s > 0) << o;
            minus |= (uint32_t)(s < 0) << o;
        }
    }
    size_t idx = (size_t)b * H2 * STRIDE + (size_t)h * STRIDE + w;
    p2[idx] = plus;
    m2[idx] = minus;
}

// 4 px/thread ternary conv -> f32; asm bcnt chains.
__global__ __launch_bounds__(256) void k_conv3(const uint32_t* __restrict__ p2,
                                               const uint32_t* __restrict__ m2,
                                               const uint32_t* __restrict__ pw3,
                                               float* __restrict__ out) {
    int gx = blockIdx.x * 64 + threadIdx.x;   // 0..127
    int h = blockIdx.y * 4 + threadIdx.y;     // 0..507
    int b = blockIdx.z;
    int w0 = gx * 4;
    if (w0 >= H2 || h >= H3) return;
    const uint32_t* pb = p2 + (size_t)b * H2 * STRIDE;
    const uint32_t* mb = m2 + (size_t)b * H2 * STRIDE;
    uint32_t pp[3][6], mm[3][6];
#pragma unroll
    for (int r = 0; r < 3; ++r) {
        const uint32_t* rp = pb + (size_t)(h + r) * STRIDE + w0;
        uint4 q = *(const uint4*)rp;
        uint2 q2 = *(const uint2*)(rp + 4);
        pp[r][0] = q.x; pp[r][1] = q.y; pp[r][2] = q.z; pp[r][3] = q.w;
        pp[r][4] = q2.x; pp[r][5] = q2.y;
        const uint32_t* rm = mb + (size_t)(h + r) * STRIDE + w0;
        uint4 u = *(const uint4*)rm;
        uint2 u2 = *(const uint2*)(rm + 4);
        mm[r][0] = u.x; mm[r][1] = u.y; mm[r][2] = u.z; mm[r][3] = u.w;
        mm[r][4] = u2.x; mm[r][5] = u2.y;
    }
    float val[2][4];
#pragma unroll
    for (int i = 0; i < 4; ++i) {
        int Ps = 0, Ms = 0;
#pragma unroll
        for (int r = 0; r < 3; ++r)
#pragma unroll
            for (int j = 0; j < 3; ++j) {
                BCNT_ACC(Ps, pp[r][i + j]);
                BCNT_ACC(Ms, mm[r][i + j]);
            }
#pragma unroll
        for (int o = 0; o < 2; ++o) {
            int Ap = 0, Am = 0;
#pragma unroll
            for (int r = 0; r < 3; ++r)
#pragma unroll
                for (int j = 0; j < 3; ++j) {
                    uint32_t wm = pw3[o * 9 + r * 3 + j];   // uniform -> SGPR
                    uint32_t ta = pp[r][i + j] & wm;
                    uint32_t tb = mm[r][i + j] & wm;
                    BCNT_ACC(Ap, ta);
                    BCNT_ACC(Am, tb);
                }
            int s = 2 * (Ap - Am) - Ps + Ms;
            val[o][i] = (s > 0) ? 1.f : ((s < 0) ? -1.f : 0.f);
        }
    }
#pragma unroll
    for (int o = 0; o < 2; ++o) {
        float* op = out + (size_t)b * (2 * H3 * H3) + (size_t)o * (H3 * H3) + (size_t)h * H3 + w0;
        *(float2*)op = make_float2(val[o][0], val[o][1]);
        if (w0 + 3 < H3)
            *(float2*)(op + 2) = make_float2(val[o][2], val[o][3]);
    }
}

extern "C" void kernel_launch(void* const* d_in, const int* in_sizes, int n_in,
                              void* d_out, int out_size, void* d_ws, size_t ws_size,
                              hipStream_t stream) {
    const float* inputs = (const float*)d_in[0];
    const float* w1 = (const float*)d_in[1];
    const float* w2 = (const float*)d_in[2];
    const float* w3 = (const float*)d_in[3];
    float* out = (float*)d_out;
    char* ws = (char*)d_ws;

    float* lw = (float*)(ws + 0);             // 448 f32 (reordered sign(w1))
    uint32_t* pw2c = (uint32_t*)(ws + 2048);  // 115 u32 (neg masks, stride 5)
    uint32_t* pw3 = (uint32_t*)(ws + 4096);   // 18 u32
    uint32_t* t1 = (uint32_t*)(ws + 8192);    // 32*510*512 u32 (L1: n | z<<16)
    size_t off_p2 = 8192 + (size_t)32 * H1 * STRIDE * 4;
    uint32_t* p2 = (uint32_t*)(ws + off_p2);  // 32*508*512 u32
    size_t off_m2 = off_p2 + (size_t)32 * H2 * STRIDE * 4;
    uint32_t* m2 = (uint32_t*)(ws + off_m2);
    size_t need = off_m2 + (size_t)32 * H2 * STRIDE * 4;
    if (ws_size < need) return;

    hipLaunchKernelGGL(k_prep, dim3(1), dim3(256), 0, stream, w1, w2, w3, lw, pw2c, pw3);
    hipLaunchKernelGGL(k_conv1, dim3(2, 64, 32), dim3(64, 4), 0, stream, inputs, lw, t1);
    hipLaunchKernelGGL(k_conv2, dim3(8, 127, 32), dim3(64, 4), 0, stream, t1, pw2c, p2, m2);
    hipLaunchKernelGGL(k_conv3, dim3(2, 127, 32), dim3(64, 4), 0, stream, p2, m2, pw3, out);
}

// Round 14
// 193.611 us; speedup vs baseline: 1.1311x; 1.1311x over previous
//
#include <hip/hip_runtime.h>
#include <stdint.h>

// Binarized 3-layer CNN — bit-exact vs float32 reference (verified r3-r13).
// Convergence build: each kernel is its best-measured variant.
// L1 (r8 form, 95.0us): f32 conv, strict sequential (kh,kw,c) per-pixel order,
//     8 px/thread, weights via wave-uniform s_load at use, C++ epilogue.
// L2 (r12 form): XOR+popcount vs NEGATIVE masks, 1 px/thread, weights via
//     uniform s_load in 3 sched_barrier-fenced chunks. Exact ternary fallback.
// L3 (r8 form): masked-popcount ternary conv, 4 px/thread.

#define H1 510
#define H2 508
#define H3 506
#define STRIDE 512

#define BCNT_ACC(acc, x) \
    asm("v_bcnt_u32_b32 %0, %1, %0" : "+v"(acc) : "v"(x))
#define FUNNEL31(word, val) \
    asm("v_alignbit_b32 %0, %0, %1, 31" : "+v"(word) : "v"(val))

__global__ __launch_bounds__(256) void k_prep(const float* __restrict__ w1,
                                              const float* __restrict__ w2,
                                              const float* __restrict__ w3,
                                              float* __restrict__ lw,
                                              uint32_t* __restrict__ pw2c,
                                              uint32_t* __restrict__ pw3) {
    int t = threadIdx.x;
    // sign(w1), order t=(r*3+j)*3+c (c fastest), padded to 28/o
    for (int i = t; i < 448; i += 256) {
        int o = i / 28, k = i % 28;
        float v = 0.f;
        if (k < 27) {
            int c = k % 3, j = (k / 3) % 3, r = k / 9;
            float wv = w1[o * 27 + c * 9 + r * 3 + j];
            v = (wv > 0.f) ? 1.f : ((wv < 0.f) ? -1.f : 0.f);
        }
        lw[i] = v;
    }
    // w2 [23][16][3][3] -> pw2c[o*5+g]: NEGATIVE-mask 16-bit channel words,
    // 2 taps/word (k0 lo16, k1 hi16); g==4 hi16 = 0. Compact stride 5.
    for (int i = t; i < 115; i += 256) {
        int o = i / 5, g = i % 5;
        int k0 = 2 * g, k1 = 2 * g + 1;
        uint32_t word = 0;
        for (int c = 0; c < 16; ++c) {
            if (!(w2[o * 144 + c * 9 + k0] > 0.f)) word |= 1u << c;
            if (k1 < 9 && !(w2[o * 144 + c * 9 + k1] > 0.f)) word |= 1u << (16 + c);
        }
        pw2c[i] = word;
    }
    // w3 [2][23][3][3] -> per (o, tap k): POSITIVE 23-bit channel mask
    for (int i = t; i < 18; i += 256) {
        int o = i / 9, k = i % 9;
        uint32_t m = 0;
        for (int c = 0; c < 23; ++c)
            if (w3[o * 207 + c * 9 + k] > 0.f) m |= 1u << c;
        pw3[i] = m;
    }
}

// 8 px/thread (4 wide x 2 tall); strict per-pixel (kh,kw,c) f32 order.
// Weights via wave-uniform global reads -> scalar loads on the SMEM pipe.
// r8-verbatim (best measured: 95.0 us). No inline asm here (r13 lesson).
__global__ __launch_bounds__(256) void k_conv1(const float* __restrict__ in,
                                               const float* __restrict__ lw_g,
                                               uint32_t* __restrict__ t1) {
    int gx = blockIdx.x * 64 + threadIdx.x;   // 0..127
    int hy = blockIdx.y * 4 + threadIdx.y;    // 0..255
    int b = blockIdx.z;
    int w0 = gx * 4;                          // 0..508
    int h0 = hy * 2;                          // 0..510
    if (h0 >= H1) return;
    const float* base = in + (size_t)b * 3 * 512 * 512;
    float x[3][4][6];
    bool tail = (w0 + 4 >= 512);
#pragma unroll
    for (int c = 0; c < 3; ++c)
#pragma unroll
        for (int r = 0; r < 4; ++r) {
            const float* rp = base + c * 262144 + (size_t)(h0 + r) * 512 + w0;
            float4 v4 = *(const float4*)rp;
            x[c][r][0] = v4.x; x[c][r][1] = v4.y; x[c][r][2] = v4.z; x[c][r][3] = v4.w;
            if (!tail) {
                float2 v2 = *(const float2*)(rp + 4);
                x[c][r][4] = v2.x; x[c][r][5] = v2.y;
            } else {
                x[c][r][4] = 0.f; x[c][r][5] = 0.f;   // feeds only px >= H1 (unread)
            }
        }
    uint32_t rn[8] = {0, 0, 0, 0, 0, 0, 0, 0};   // sign-bit planes
    uint32_t rz[8] = {0, 0, 0, 0, 0, 0, 0, 0};   // NONZERO-bit planes
#pragma unroll 1
    for (int o = 15; o >= 0; --o) {              // o order irrelevant to rounding
        const float* wo = lw_g + o * 28;         // uniform address -> s_load
        float s[8];
#pragma unroll
        for (int p = 0; p < 8; ++p) s[p] = 0.f;
#pragma unroll
        for (int t = 0; t < 27; ++t) {           // ascending t = (r*3+j)*3+c
            float wv = wo[t];
            int c = t % 3, j = (t / 3) % 3, r = t / 9;
#pragma unroll
            for (int pr = 0; pr < 2; ++pr)
#pragma unroll
                for (int pc = 0; pc < 4; ++pc)
                    s[pr * 4 + pc] = fmaf(x[c][pr + r][pc + j], wv, s[pr * 4 + pc]);
        }
#pragma unroll
        for (int p = 0; p < 8; ++p) {
            uint32_t u = __float_as_uint(s[p]);
            rn[p] = (rn[p] << 1) | (u >> 31);
            uint32_t nz = u | (0u - u);          // sign set iff u != 0
            rz[p] = (rz[p] << 1) | (nz >> 31);
        }
    }
    uint32_t* dst = t1 + (size_t)b * H1 * STRIDE;
#pragma unroll
    for (int pr = 0; pr < 2; ++pr) {
        uint32_t w4[4];
#pragma unroll
        for (int pc = 0; pc < 4; ++pc)
            w4[pc] = rn[pr * 4 + pc] | (~rz[pr * 4 + pc] << 16);  // n lo16 | z hi16
        *(uint4*)(dst + (size_t)(h0 + pr) * STRIDE + w0) =
            make_uint4(w4[0], w4[1], w4[2], w4[3]);
    }
}

// 1 px/thread; weights via uniform s_load (SGPRs), chunked to bound pressure.
// r12-verbatim.
__global__ __launch_bounds__(256) void k_conv2(const uint32_t* __restrict__ t1,
                                               const uint32_t* __restrict__ wc5,
                                               uint32_t* __restrict__ p2,
                                               uint32_t* __restrict__ m2) {
    int w = blockIdx.x * 64 + threadIdx.x;
    int h = blockIdx.y * 4 + threadIdx.y;
    int b = blockIdx.z;
    if (w >= H2 || h >= H2) return;
    const uint32_t* base = t1 + (size_t)b * H1 * STRIDE;
    uint32_t A[9];
#pragma unroll
    for (int r = 0; r < 3; ++r)
#pragma unroll
        for (int j = 0; j < 3; ++j)
            A[r * 3 + j] = base[(size_t)(h + r) * STRIDE + (w + j)];
    uint32_t orall = A[0] | A[1] | A[2] | A[3] | A[4] | A[5] | A[6] | A[7] | A[8];
    // n-plane packed 2 taps/word via byte-perm
    uint32_t N0 = __builtin_amdgcn_perm(A[1], A[0], 0x05040100u);
    uint32_t N1 = __builtin_amdgcn_perm(A[3], A[2], 0x05040100u);
    uint32_t N2 = __builtin_amdgcn_perm(A[5], A[4], 0x05040100u);
    uint32_t N3 = __builtin_amdgcn_perm(A[7], A[6], 0x05040100u);
    uint32_t N4 = A[8] & 0xFFFFu;
    uint32_t plus = 0, minus = 0;
    if ((orall >> 16) == 0) {
        // FAST: all 144 activations +-1. d = popc_mismatch - 72; o descending.
#define C2O(o) do { \
        uint32_t q0 = wc5[(o) * 5 + 0], q1 = wc5[(o) * 5 + 1], \
                 q2 = wc5[(o) * 5 + 2], q3 = wc5[(o) * 5 + 3], \
                 q4 = wc5[(o) * 5 + 4]; \
        uint32_t t0 = N0 ^ q0, t1v = N1 ^ q1, t2v = N2 ^ q2, \
                 t3v = N3 ^ q3, t4v = N4 ^ q4; \
        int cnt = -72; \
        BCNT_ACC(cnt, t0); BCNT_ACC(cnt, t1v); BCNT_ACC(cnt, t2v); \
        BCNT_ACC(cnt, t3v); BCNT_ACC(cnt, t4v); \
        int nd = -cnt; \
        FUNNEL31(plus, cnt); \
        FUNNEL31(minus, nd); \
    } while (0)
        C2O(22); C2O(21); C2O(20); C2O(19); C2O(18); C2O(17); C2O(16); C2O(15);
        __builtin_amdgcn_sched_barrier(0);
        C2O(14); C2O(13); C2O(12); C2O(11); C2O(10); C2O(9); C2O(8); C2O(7);
        __builtin_amdgcn_sched_barrier(0);
        C2O(6); C2O(5); C2O(4); C2O(3); C2O(2); C2O(1); C2O(0);
#undef C2O
    } else {
        // RARE: window contains an exact-zero L1 activation -> exact ternary.
        uint32_t P[5], M[5];
        {
            uint32_t p16[9], m16[9];
#pragma unroll
            for (int k = 0; k < 9; ++k) {
                uint32_t z = A[k] >> 16;
                p16[k] = (~(A[k] | z)) & 0xFFFFu;
                m16[k] = (A[k] & ~z) & 0xFFFFu;
            }
            P[0] = p16[0] | (p16[1] << 16); M[0] = m16[0] | (m16[1] << 16);
            P[1] = p16[2] | (p16[3] << 16); M[1] = m16[2] | (m16[3] << 16);
            P[2] = p16[4] | (p16[5] << 16); M[2] = m16[4] | (m16[5] << 16);
            P[3] = p16[6] | (p16[7] << 16); M[3] = m16[6] | (m16[7] << 16);
            P[4] = p16[8];                  M[4] = m16[8];
        }
        int sp = 0, sm = 0;
#pragma unroll
        for (int g = 0; g < 5; ++g) {
            sp += __builtin_popcount(P[g]);
            sm += __builtin_popcount(M[g]);
        }
#pragma unroll
        for (int o = 0; o < 23; ++o) {
            int ap = 0, am = 0;
#pragma unroll
            for (int g = 0; g < 5; ++g) {
                uint32_t Wn = wc5[o * 5 + g];   // uniform s_load
                ap += __builtin_popcount(P[g] & Wn);
                am += __builtin_popcount(M[g] & Wn);
            }
            int s = sp - sm + 2 * (am - ap);
            plus  |= (uint32_t)(s > 0) << o;
            minus |= (uint32_t)(s < 0) << o;
        }
    }
    size_t idx = (size_t)b * H2 * STRIDE + (size_t)h * STRIDE + w;
    p2[idx] = plus;
    m2[idx] = minus;
}

// 4 px/thread ternary conv -> f32; asm bcnt chains. r8-verbatim.
__global__ __launch_bounds__(256) void k_conv3(const uint32_t* __restrict__ p2,
                                               const uint32_t* __restrict__ m2,
                                               const uint32_t* __restrict__ pw3,
                                               float* __restrict__ out) {
    int gx = blockIdx.x * 64 + threadIdx.x;   // 0..127
    int h = blockIdx.y * 4 + threadIdx.y;     // 0..507
    int b = blockIdx.z;
    int w0 = gx * 4;
    if (w0 >= H2 || h >= H3) return;
    const uint32_t* pb = p2 + (size_t)b * H2 * STRIDE;
    const uint32_t* mb = m2 + (size_t)b * H2 * STRIDE;
    uint32_t pp[3][6], mm[3][6];
#pragma unroll
    for (int r = 0; r < 3; ++r) {
        const uint32_t* rp = pb + (size_t)(h + r) * STRIDE + w0;
        uint4 q = *(const uint4*)rp;
        uint2 q2 = *(const uint2*)(rp + 4);
        pp[r][0] = q.x; pp[r][1] = q.y; pp[r][2] = q.z; pp[r][3] = q.w;
        pp[r][4] = q2.x; pp[r][5] = q2.y;
        const uint32_t* rm = mb + (size_t)(h + r) * STRIDE + w0;
        uint4 u = *(const uint4*)rm;
        uint2 u2 = *(const uint2*)(rm + 4);
        mm[r][0] = u.x; mm[r][1] = u.y; mm[r][2] = u.z; mm[r][3] = u.w;
        mm[r][4] = u2.x; mm[r][5] = u2.y;
    }
    float val[2][4];
#pragma unroll
    for (int i = 0; i < 4; ++i) {
        int Ps = 0, Ms = 0;
#pragma unroll
        for (int r = 0; r < 3; ++r)
#pragma unroll
            for (int j = 0; j < 3; ++j) {
                BCNT_ACC(Ps, pp[r][i + j]);
                BCNT_ACC(Ms, mm[r][i + j]);
            }
#pragma unroll
        for (int o = 0; o < 2; ++o) {
            int Ap = 0, Am = 0;
#pragma unroll
            for (int r = 0; r < 3; ++r)
#pragma unroll
                for (int j = 0; j < 3; ++j) {
                    uint32_t wm = pw3[o * 9 + r * 3 + j];   // uniform -> SGPR
                    uint32_t ta = pp[r][i + j] & wm;
                    uint32_t tb = mm[r][i + j] & wm;
                    BCNT_ACC(Ap, ta);
                    BCNT_ACC(Am, tb);
                }
            int s = 2 * (Ap - Am) - Ps + Ms;
            val[o][i] = (s > 0) ? 1.f : ((s < 0) ? -1.f : 0.f);
        }
    }
#pragma unroll
    for (int o = 0; o < 2; ++o) {
        float* op = out + (size_t)b * (2 * H3 * H3) + (size_t)o * (H3 * H3) + (size_t)h * H3 + w0;
        *(float2*)op = make_float2(val[o][0], val[o][1]);
        if (w0 + 3 < H3)
            *(float2*)(op + 2) = make_float2(val[o][2], val[o][3]);
    }
}

extern "C" void kernel_launch(void* const* d_in, const int* in_sizes, int n_in,
                              void* d_out, int out_size, void* d_ws, size_t ws_size,
                              hipStream_t stream) {
    const float* inputs = (const float*)d_in[0];
    const float* w1 = (const float*)d_in[1];
    const float* w2 = (const float*)d_in[2];
    const float* w3 = (const float*)d_in[3];
    float* out = (float*)d_out;
    char* ws = (char*)d_ws;

    float* lw = (float*)(ws + 0);             // 448 f32 (reordered sign(w1))
    uint32_t* pw2c = (uint32_t*)(ws + 2048);  // 115 u32 (neg masks, stride 5)
    uint32_t* pw3 = (uint32_t*)(ws + 4096);   // 18 u32
    uint32_t* t1 = (uint32_t*)(ws + 8192);    // 32*510*512 u32 (L1: n | z<<16)
    size_t off_p2 = 8192 + (size_t)32 * H1 * STRIDE * 4;
    uint32_t* p2 = (uint32_t*)(ws + off_p2);  // 32*508*512 u32
    size_t off_m2 = off_p2 + (size_t)32 * H2 * STRIDE * 4;
    uint32_t* m2 = (uint32_t*)(ws + off_m2);
    size_t need = off_m2 + (size_t)32 * H2 * STRIDE * 4;
    if (ws_size < need) return;

    hipLaunchKernelGGL(k_prep, dim3(1), dim3(256), 0, stream, w1, w2, w3, lw, pw2c, pw3);
    hipLaunchKernelGGL(k_conv1, dim3(2, 64, 32), dim3(64, 4), 0, stream, inputs, lw, t1);
    hipLaunchKernelGGL(k_conv2, dim3(8, 127, 32), dim3(64, 4), 0, stream, t1, pw2c, p2, m2);
    hipLaunchKernelGGL(k_conv3, dim3(2, 127, 32), dim3(64, 4), 0, stream, p2, m2, pw3, out);
}